// Round 2
// baseline (7790.864 us; speedup 1.0000x reference)
//
#include <hip/hip_runtime.h>
#include <cstdint>

// Persistent fp16-MFMA 3-layer autoregressive LSTM. B=64,T=512,F=132,H=1024.
// Round 9: de-risked variant of R8. Keeps R7's PROVEN agent-scope sync
// (flat 2-level global barrier + per-XCD stage counter) and retains only the
// deadlock-free improvements:
//  (b) compute phases hoist all 16 A-frag buffer-loads into an array before
//      the MFMA loop (16 in flight cover ~300cy L2 latency; 240 VGPR total,
//      still in the 2-waves/SIMD bucket); decoder loads hoisted likewise.
//  (c) stage loads issued first, acc-init under their L3 latency; x-phase
//      MFMAs run between xsync-arrive and xsync-poll (independent of staged
//      data) to hide other blocks' staging skew.
// R8's workgroup-scope/L2-local barrier is intentionally NOT included: it is
// the only candidate cause of the R8 bench failure and must be re-introduced
// alone, once a clean baseline for (b)+(c) exists.

#define NBLK 256
#define NTHR 512
#define Bn 64
#define Tn 512
#define Fn 132
#define Hn 1024
#define TF (Tn * Fn)          // 67584
#define SRCH 65536            // halfs per h source (64*1024), layout [k8][b][8]
#define HBUF 196608           // halfs per h buffer (3 sources)
#define XTT 10240             // halfs per timestep of xT (20 k8 * 64 * 8)
#define WPB 102400            // halfs of weight blob per block (8 waves * 25 slots * 512)
#define STB 393216            // bytes per staged h image (3*64*1024*2)
#define STU 49152             // 8B units per staged image

typedef _Float16 h8 __attribute__((ext_vector_type(8)));
typedef float f4 __attribute__((ext_vector_type(4)));
typedef int v4i __attribute__((ext_vector_type(4)));
typedef unsigned long long ull;

// Raw buffer load, compiler-tracked vmcnt, aux=1 -> sc0 (L1 bypass, L2 hit).
__device__ v4i llvm_amdgcn_raw_buffer_load_v4i32(v4i srsrc, int voffset,
                                                 int soffset, int aux)
    __asm("llvm.amdgcn.raw.buffer.load.v4i32");

__device__ __forceinline__ v4i make_srd(const void* p) {
    union { struct { unsigned lo, hi, sz, cfg; } s; v4i v; } u;
    u.s.lo = (unsigned)(uintptr_t)p;
    u.s.hi = (unsigned)((uintptr_t)p >> 32); // stride=0
    u.s.sz = 0xFFFFFFFFu;                    // disable bounds check
    u.s.cfg = 0x00020000u;                   // raw dword access
    return u.v;
}

__device__ __forceinline__ h8 bload16(v4i rsrc, int voff) {
    union { v4i i; h8 h; } c;
    c.i = llvm_amdgcn_raw_buffer_load_v4i32(rsrc, voff, 0, 1 /*sc0*/);
    return c.h;
}

__device__ __forceinline__ float sigf(float x) { return 1.0f / (1.0f + expf(-x)); }

__device__ __forceinline__ ull cload8(const void* p) {
    return __hip_atomic_load((const ull*)p, __ATOMIC_RELAXED, __HIP_MEMORY_SCOPE_AGENT);
}
__device__ __forceinline__ void cstore8(void* p, ull v) {
    __hip_atomic_store((ull*)p, v, __ATOMIC_RELAXED, __HIP_MEMORY_SCOPE_AGENT);
}

// Global barrier pieces (2-level relaxed arrive, relaxed poll). Proven in R7.
__device__ __forceinline__ void garrive(unsigned* bar, unsigned ep) {
    unsigned* cnt = bar + ((blockIdx.x >> 5) << 5);
    unsigned old = __hip_atomic_fetch_add(cnt, 1u, __ATOMIC_RELAXED,
                                          __HIP_MEMORY_SCOPE_AGENT);
    if (old == 32u * ep - 1u) {
        unsigned d = __hip_atomic_fetch_add(bar + 256, 1u, __ATOMIC_RELAXED,
                                            __HIP_MEMORY_SCOPE_AGENT);
        if (d == 8u * ep - 1u)
            __hip_atomic_store(bar + 288, ep, __ATOMIC_RELAXED,
                               __HIP_MEMORY_SCOPE_AGENT);
    }
}
__device__ __forceinline__ void gwait(unsigned* bar, unsigned ep) {
    while (__hip_atomic_load(bar + 288, __ATOMIC_RELAXED,
                             __HIP_MEMORY_SCOPE_AGENT) < ep)
        __builtin_amdgcn_s_sleep(1);
}
__device__ __forceinline__ void gsyncA(unsigned* bar, unsigned ep) {
    __syncthreads();
    if (threadIdx.x == 0) { garrive(bar, ep); gwait(bar, ep); }
    __syncthreads();
}

// ---------------- convert kernels (once per launch) -------------------------

__global__ void k_bsum(const float* bih1, const float* bhh1, const float* bih2,
                       const float* bhh2, const float* bih3, const float* bhh3,
                       const float* Wih1, const float* bd,
                       float* bsum, float* bsum2) {
    int i = blockIdx.x * 256 + threadIdx.x;
    if (i < NBLK * 48) {
        int bidw = i / 48, r = i % 48;
        int cell = r >> 4, n = r & 15;
        int row = (n >> 2) * Hn + bidw * 4 + (n & 3);
        const float* bi = cell == 0 ? bih1 : (cell == 1 ? bih2 : bih3);
        const float* bh = cell == 0 ? bhh1 : (cell == 1 ? bhh2 : bhh3);
        bsum[i] = bi[row] + bh[row];
    } else if (i < NBLK * 64) {
        int ii = i - NBLK * 48;
        int bidw = ii / 16, n = ii % 16;
        int row = (n >> 2) * Hn + bidw * 4 + (n & 3);
        float s = 0.0f;
        for (int f = 0; f < Fn; ++f) s += Wih1[(size_t)row * Fn + f] * bd[f];
        bsum2[bidw * 16 + n] = s;
    }
}

__global__ void k_convx(const float* xseq, _Float16* xT) {
    int i = blockIdx.x * 256 + threadIdx.x;
    if (i >= Tn * XTT) return;
    int t = i / XTT, r = i % XTT;
    int k8 = r >> 9, b = (r >> 3) & 63, e = r & 7;
    int f = k8 * 8 + e;
    float v = (f < Fn) ? xseq[((size_t)b * Tn + t) * Fn + f] : 0.0f;
    xT[i] = (_Float16)v;
}

// Weight blob: [block][wave][slot 0..24][frag 512 halfs].
// slot 0-3: Whh1 kt=w*4+s | 4-7: Wih2 | 8-11: Whh2 | 12-15: Wih3 | 16-19: Whh3
// slot 20: Wih1 kt=w (waves 0-4) | slot 21-24: W1d = Wih1@Wd.
__global__ void k_convw(const float* Wih1, const float* Whh1, const float* Wih2,
                        const float* Whh2, const float* Wih3, const float* Whh3,
                        const float* Wd, _Float16* wblob) {
    int i = blockIdx.x * 256 + threadIdx.x;
    if (i >= NBLK * WPB) return;
    int bidw = i / WPB, r = i % WPB;
    int slot = r >> 9, e = r & 511;
    int w = slot / 25, s = slot - w * 25;
    int l = e >> 3, j = e & 7;
    int kq = l >> 4, n = l & 15;
    int row = (n >> 2) * Hn + bidw * 4 + (n & 3);
    float v = 0.0f;
    if (s >= 21) {
        int kt = w * 4 + (s - 21);
        int k = kt * 32 + kq * 8 + j;
        float acc = 0.0f;
        for (int f = 0; f < Fn; ++f)
            acc += Wih1[(size_t)row * Fn + f] * Wd[(size_t)f * Hn + k];
        v = acc;
    } else {
        const float* M;
        int K, kt;
        if (s < 4)       { M = Whh1; K = Hn; kt = w * 4 + s; }
        else if (s < 8)  { M = Wih2; K = Hn; kt = w * 4 + s - 4; }
        else if (s < 12) { M = Whh2; K = Hn; kt = w * 4 + s - 8; }
        else if (s < 16) { M = Wih3; K = Hn; kt = w * 4 + s - 12; }
        else if (s < 20) { M = Whh3; K = Hn; kt = w * 4 + s - 16; }
        else             { M = Wih1; K = Fn; kt = w; }
        int k = kt * 32 + kq * 8 + j;
        if (!(s == 20 && w >= 5) && k < K) v = M[(size_t)row * K + k];
    }
    wblob[i] = (_Float16)v;
}

__global__ void k_misc(_Float16* hT) {
    int i = blockIdx.x * 256 + threadIdx.x;
    if (i < HBUF) hT[i] = (_Float16)0.0f;
}

// ---------------- persistent kernel ----------------------------------------

__global__ __launch_bounds__(NTHR, 2) void lstm_mfma(
    const _Float16* __restrict__ xT, const _Float16* __restrict__ wblob,
    _Float16* __restrict__ hT, unsigned char* __restrict__ xstage,
    const float* __restrict__ bsum, const float* __restrict__ bsum2,
    const float* __restrict__ Wd, const float* __restrict__ bd,
    const int* __restrict__ cnum_p, const int* __restrict__ gnum_p,
    float* __restrict__ dout, unsigned* __restrict__ bar) {
    __shared__ float red[8 * 12 * 68 * 4];     // 102 KB reduce scratch
    __shared__ float cst[768];                 // c state [cell][jj][b]
    __shared__ float sbias[48];
    __shared__ float sbias2[16];
    __shared__ unsigned long long hstage[192];
    __shared__ int sxi[3];                     // xcd, rank, Nx

    const int tid = threadIdx.x;
    const int bid = blockIdx.x;
    const int lane = tid & 63;
    const int wid = tid >> 6;
    const int laneAB = (lane >> 4) * 1024 + (lane & 15) * 16; // A-frag byte off
    const int laneA0 = (lane >> 4) * 512 + (lane & 15) * 8;   // same, halfs
    const int widB = wid * 16384;

    if (tid < 48) sbias[tid] = bsum[bid * 48 + tid];
    if (tid >= 64 && tid < 80) sbias2[tid - 64] = bsum2[bid * 16 + (tid - 64)];
    for (int i = tid; i < 768; i += NTHR) cst[i] = 0.0f;

    // Weight fragments -> registers, once.
    h8 wfr[25];
    {
        const _Float16* wp = wblob + (size_t)bid * WPB + (size_t)(wid * 25) * 512 + lane * 8;
#pragma unroll
        for (int s2 = 0; s2 < 25; ++s2) wfr[s2] = *(const h8*)(wp + s2 * 512);
    }

    // ---- XCD registration (dispatch->XCD mapping is undefined; discover) ----
    if (tid == 0) {
        unsigned x;
        asm volatile("s_getreg_b32 %0, hwreg(HW_REG_XCC_ID)" : "=s"(x));
        x &= 7u;
        unsigned r = __hip_atomic_fetch_add(bar + 384 + x * 16, 1u,
                                            __ATOMIC_RELAXED, __HIP_MEMORY_SCOPE_AGENT);
        sxi[0] = (int)x; sxi[1] = (int)r;
    }
    gsyncA(bar, 1); // all registered
    if (tid == 0)
        sxi[2] = (int)__hip_atomic_load(bar + 384 + sxi[0] * 16, __ATOMIC_RELAXED,
                                        __HIP_MEMORY_SCOPE_AGENT);
    __syncthreads();
    const int xcd = sxi[0], xrank = sxi[1], xN = sxi[2];
    unsigned* xb = bar + 640 + xcd * 16;
    unsigned char* xsb = xstage + (size_t)xcd * 2 * STB;

    const int gnum = gnum_p[0];
    const int per = gnum + cnum_p[0];

    // Decoder for output row tt, reading staged h2 via rsrc (all threads).
    // 8 h-loads hoisted into an array so all are in flight before first use.
    auto decoder = [&](v4i rsrc, int tt) {
        const int ss = tid >> 6, b = tid & 63;
        const int nj = (bid < 8) ? 2 : 1;
        for (int j2 = 0; j2 < nj; ++j2) {
            int f, half;
            if (j2 == 0) {
                if (bid < Fn) { f = bid; half = 0; }
                else          { f = bid - Fn; half = 1; }
            } else { f = bid + (NBLK - Fn); half = 1; }
            const float* wdr = Wd + (size_t)f * Hn;
            h8 hv[8];
#pragma unroll
            for (int i = 0; i < 8; ++i) {
                const int k8 = half * 64 + ss * 8 + i;
                hv[i] = bload16(rsrc, 262144 + k8 * 1024 + b * 16);
            }
            float p = 0.0f;
#pragma unroll
            for (int i = 0; i < 8; ++i) {
                const int k8 = half * 64 + ss * 8 + i;
                const float4 w0 = *(const float4*)(wdr + k8 * 8);
                const float4 w1 = *(const float4*)(wdr + k8 * 8 + 4);
                p = fmaf((float)hv[i][0], w0.x, p); p = fmaf((float)hv[i][1], w0.y, p);
                p = fmaf((float)hv[i][2], w0.z, p); p = fmaf((float)hv[i][3], w0.w, p);
                p = fmaf((float)hv[i][4], w1.x, p); p = fmaf((float)hv[i][5], w1.y, p);
                p = fmaf((float)hv[i][6], w1.z, p); p = fmaf((float)hv[i][7], w1.w, p);
            }
            red[ss * 64 + b] = p;
            __syncthreads();
            if (tid < 64) {
                float o = (half == 0) ? bd[f] : 0.0f;
#pragma unroll
                for (int u = 0; u < 8; ++u) o += red[u * 64 + tid];
                unsafeAtomicAdd(&dout[(size_t)tid * TF + (size_t)tt * Fn + f], o);
            }
            __syncthreads();
        }
    };

    // Generic stage (tail path): agent reads, plain L2 write-back stores.
    auto stageT = [&](int rbuf, int slot) {
        const ull* src = (const ull*)(hT + (size_t)rbuf * HBUF);
        ull* dst = (ull*)(xsb + (size_t)slot * STB);
        for (int s2 = xrank; s2 < 32; s2 += xN) {
            const int u = s2 * 1536 + tid;
#pragma unroll
            for (int q = 0; q < 3; ++q)
                dst[u + q * 512] = cload8(src + u + q * 512);
        }
        __syncthreads(); // drain staging stores before arrival
    };
    // xsync split into arrive + poll so independent work can sit between.
    auto xarrive = [&]() {
        if (tid == 0)
            __hip_atomic_fetch_add(xb, 1u, __ATOMIC_RELAXED, __HIP_MEMORY_SCOPE_AGENT);
    };
    auto xpoll = [&](unsigned target) {
        if (tid == 0)
            while (__hip_atomic_load(xb, __ATOMIC_RELAXED, __HIP_MEMORY_SCOPE_AGENT) < target)
                __builtin_amdgcn_s_sleep(1);
        __syncthreads();
    };

    int tmod = 0;
    for (int t = 0; t < Tn; ++t) {
        const int flag = (tmod < gnum) ? 1 : 0;
        const bool fused = (!flag) && (t > 0);
        const int rb = t % 3, wb2 = (t + 1) % 3;
        _Float16* hw = hT + (size_t)wb2 * HBUF;

        // ---- stage h(t-1) image into this XCD's L2 (loads issued first,
        //      acc-init runs under their L3 latency) ----
        const ull* ssrc = (const ull*)(hT + (size_t)rb * HBUF);
        ull* sdst = (ull*)(xsb + (size_t)(t & 1) * STB);
        ull sv0 = 0, sv1 = 0, sv2 = 0;
        int u0 = -1;
        if (xrank < 32) {
            u0 = xrank * 1536 + tid;
            sv0 = cload8(ssrc + u0);
            sv1 = cload8(ssrc + u0 + 512);
            sv2 = cload8(ssrc + u0 + 1024);
        }
        f4 acc[12]; // [cell][mt]
#pragma unroll
        for (int i = 0; i < 12; ++i) acc[i] = (f4){0.f, 0.f, 0.f, 0.f};
        if (u0 >= 0) { sdst[u0] = sv0; sdst[u0 + 512] = sv1; sdst[u0 + 1024] = sv2; }
        for (int s2 = xrank + xN; s2 < 32; s2 += xN) { // only if xN < 32
            const int u = s2 * 1536 + tid;
#pragma unroll
            for (int q = 0; q < 3; ++q)
                sdst[u + q * 512] = cload8(ssrc + u + q * 512);
        }
        __syncthreads(); // all staging stores of this block drained
        xarrive();

        // x phase (TF steps): independent of staged data -> runs inside the
        // xsync window, hiding other blocks' staging skew.
        if (flag && wid < 5) {
            const _Float16* x0 = xT + (size_t)t * XTT + wid * 2048 + laneA0;
            h8 xa[4];
#pragma unroll
            for (int mt = 0; mt < 4; ++mt) xa[mt] = *(const h8*)(x0 + mt * 128);
#pragma unroll
            for (int mt = 0; mt < 4; ++mt)
                acc[mt] = __builtin_amdgcn_mfma_f32_16x16x32_f16(xa[mt], wfr[20], acc[mt], 0, 0, 0);
        }
        xpoll((unsigned)(xN * (t + 1)));
        const v4i rsrc = make_srd(xsb + (size_t)(t & 1) * STB);

        // h0: Whh1 -> cell0, Wih2 -> cell1 (staged, sc0 L2 hits; 16 loads in flight)
        {
            h8 a[16];
#pragma unroll
            for (int i2 = 0; i2 < 4; ++i2)
#pragma unroll
                for (int mt = 0; mt < 4; ++mt)
                    a[i2 * 4 + mt] = bload16(rsrc, widB + i2 * 4096 + mt * 256 + laneAB);
#pragma unroll
            for (int i2 = 0; i2 < 4; ++i2)
#pragma unroll
                for (int mt = 0; mt < 4; ++mt) {
                    acc[mt]     = __builtin_amdgcn_mfma_f32_16x16x32_f16(a[i2 * 4 + mt], wfr[i2],     acc[mt],     0, 0, 0);
                    acc[4 + mt] = __builtin_amdgcn_mfma_f32_16x16x32_f16(a[i2 * 4 + mt], wfr[4 + i2], acc[4 + mt], 0, 0, 0);
                }
        }
        // h1: Whh2 -> cell1, Wih3 -> cell2
        {
            h8 a[16];
#pragma unroll
            for (int i2 = 0; i2 < 4; ++i2)
#pragma unroll
                for (int mt = 0; mt < 4; ++mt)
                    a[i2 * 4 + mt] = bload16(rsrc, 131072 + widB + i2 * 4096 + mt * 256 + laneAB);
#pragma unroll
            for (int i2 = 0; i2 < 4; ++i2)
#pragma unroll
                for (int mt = 0; mt < 4; ++mt) {
                    acc[4 + mt] = __builtin_amdgcn_mfma_f32_16x16x32_f16(a[i2 * 4 + mt], wfr[8 + i2],  acc[4 + mt], 0, 0, 0);
                    acc[8 + mt] = __builtin_amdgcn_mfma_f32_16x16x32_f16(a[i2 * 4 + mt], wfr[12 + i2], acc[8 + mt], 0, 0, 0);
                }
        }
        // h2: Whh3 -> cell2; AR steps also W1d -> cell0 (same A-frags)
        {
            h8 a[16];
#pragma unroll
            for (int i2 = 0; i2 < 4; ++i2)
#pragma unroll
                for (int mt = 0; mt < 4; ++mt)
                    a[i2 * 4 + mt] = bload16(rsrc, 262144 + widB + i2 * 4096 + mt * 256 + laneAB);
            if (fused) {
#pragma unroll
                for (int i2 = 0; i2 < 4; ++i2)
#pragma unroll
                    for (int mt = 0; mt < 4; ++mt) {
                        acc[8 + mt] = __builtin_amdgcn_mfma_f32_16x16x32_f16(a[i2 * 4 + mt], wfr[16 + i2], acc[8 + mt], 0, 0, 0);
                        acc[mt]     = __builtin_amdgcn_mfma_f32_16x16x32_f16(a[i2 * 4 + mt], wfr[21 + i2], acc[mt],     0, 0, 0);
                    }
            } else {
#pragma unroll
                for (int i2 = 0; i2 < 4; ++i2)
#pragma unroll
                    for (int mt = 0; mt < 4; ++mt)
                        acc[8 + mt] = __builtin_amdgcn_mfma_f32_16x16x32_f16(a[i2 * 4 + mt], wfr[16 + i2], acc[8 + mt], 0, 0, 0);
            }
        }

        // ---- 8-way K-reduce + gates + state update ----
        {
            float* wr = red + ((size_t)(wid * 12) * 68 + (lane >> 4) * 17 + (lane & 15)) * 4;
#pragma unroll
            for (int cc = 0; cc < 3; ++cc)
#pragma unroll
                for (int mt = 0; mt < 4; ++mt)
                    *(f4*)(wr + (cc * 4 + mt) * 68 * 4) = acc[cc * 4 + mt];
        }
        __syncthreads();
        const float bmul = fused ? 1.0f : 0.0f;
        for (int idx = tid; idx < 768; idx += NTHR) {
            const int cell = idx >> 8, jj = (idx >> 6) & 3, b = idx & 63;
            const int mt = b >> 4, mq = (b >> 2) & 3, rr = b & 3;
            float gv4[4];
#pragma unroll
            for (int gt = 0; gt < 4; ++gt) {
                const int n = gt * 4 + jj;
                float v = sbias[cell * 16 + n];
                if (cell == 0) v += bmul * sbias2[n];
#pragma unroll
                for (int w2 = 0; w2 < 8; ++w2)
                    v += red[(((w2 * 12 + cell * 4 + mt)) * 68 + mq * 17 + n) * 4 + rr];
                gv4[gt] = v;
            }
            const float cold = cst[(cell * 4 + jj) * 64 + b];
            const float cn = sigf(gv4[1]) * cold + sigf(gv4[0]) * tanhf(gv4[2]);
            cst[(cell * 4 + jj) * 64 + b] = cn;
            const float hn = sigf(gv4[3]) * tanhf(cn);
            ((_Float16*)hstage)[(cell * 64 + b) * 4 + jj] = (_Float16)hn;
        }
        __syncthreads();
        if (tid < 192) { // pack 4 halfs -> one coherent 8B store to hT
            const int cell = tid >> 6, b = tid & 63;
            _Float16* dst = hw + cell * SRCH + (bid >> 1) * 512 + b * 8 + 4 * (bid & 1);
            cstore8(dst, hstage[tid]);
        }

        // ---- global barrier with decoder hidden in the wait window ----
        __syncthreads(); // drain h stores before arrival
        if (tid == 0) garrive(bar, (unsigned)(t + 2));
        if (t > 0) decoder(rsrc, t - 1); // staged slot t&1 holds h(t-1) image
        __syncthreads();
        if (tid == 0) gwait(bar, (unsigned)(t + 2));
        __syncthreads();

        tmod = (tmod + 1 >= per) ? 0 : (tmod + 1);
    }

    // Tail: stage the final h image and emit dout[Tn-1].
    stageT(Tn % 3, Tn & 1);
    if (tid == 0) {
        __hip_atomic_fetch_add(xb, 1u, __ATOMIC_RELAXED, __HIP_MEMORY_SCOPE_AGENT);
        while (__hip_atomic_load(xb, __ATOMIC_RELAXED, __HIP_MEMORY_SCOPE_AGENT)
               < (unsigned)(xN * (Tn + 1)))
            __builtin_amdgcn_s_sleep(1);
    }
    __syncthreads();
    decoder(make_srd(xsb + (size_t)(Tn & 1) * STB), Tn - 1);
}

// ---------------- host ------------------------------------------------------

extern "C" void kernel_launch(void* const* d_in, const int* in_sizes, int n_in,
                              void* d_out, int out_size, void* d_ws, size_t ws_size,
                              hipStream_t stream) {
    const float* xseq = (const float*)d_in[0];
    const float* Wih1 = (const float*)d_in[1];
    const float* Whh1 = (const float*)d_in[2];
    const float* bih1 = (const float*)d_in[3];
    const float* bhh1 = (const float*)d_in[4];
    const float* Wih2 = (const float*)d_in[5];
    const float* Whh2 = (const float*)d_in[6];
    const float* bih2 = (const float*)d_in[7];
    const float* bhh2 = (const float*)d_in[8];
    const float* Wih3 = (const float*)d_in[9];
    const float* Whh3 = (const float*)d_in[10];
    const float* bih3 = (const float*)d_in[11];
    const float* bhh3 = (const float*)d_in[12];
    const float* Wd = (const float*)d_in[13];
    const float* bd = (const float*)d_in[14];
    const int* cnum_p = (const int*)d_in[15];
    const int* gnum_p = (const int*)d_in[16];

    unsigned char* ws = (unsigned char*)d_ws;
    unsigned* bar = (unsigned*)ws;                       // 4096 B (gbar/reg/xbar)
    float* bsum = (float*)(ws + 4096);                   // NBLK*48 f32
    float* bsum2 = (float*)(ws + 53248);                 // NBLK*16 f32
    _Float16* xT = (_Float16*)(ws + 102400);             // 10,485,760 B
    _Float16* wblob = (_Float16*)(ws + 102400 + 10485760);           // 52,428,800 B
    _Float16* hT = (_Float16*)(ws + 102400 + 10485760 + 52428800);   // 1,179,648 B
    unsigned char* xstage = ws + 102400 + 10485760 + 52428800 + 1179648; // 6,291,456 B

    hipMemsetAsync(bar, 0, 4096, stream);
    hipMemsetAsync(d_out, 0, (size_t)out_size * sizeof(float), stream);
    hipLaunchKernelGGL(k_bsum, dim3((NBLK * 64 + 255) / 256), dim3(256), 0, stream,
                       bih1, bhh1, bih2, bhh2, bih3, bhh3, Wih1, bd, bsum, bsum2);
    hipLaunchKernelGGL(k_convx, dim3((Tn * XTT + 255) / 256), dim3(256), 0, stream,
                       xseq, xT);
    hipLaunchKernelGGL(k_convw, dim3((NBLK * WPB + 255) / 256), dim3(256), 0, stream,
                       Wih1, Whh1, Wih2, Whh2, Wih3, Whh3, Wd, wblob);
    hipLaunchKernelGGL(k_misc, dim3((HBUF + 255) / 256), dim3(256), 0, stream, hT);
    hipLaunchKernelGGL(lstm_mfma, dim3(NBLK), dim3(NTHR), 0, stream,
                       xT, wblob, hT, xstage, bsum, bsum2, Wd, bd, cnum_p, gnum_p,
                       (float*)d_out, bar);
}